// Round 3
// baseline (115.109 us; speedup 1.0000x reference)
//
#include <hip/hip_runtime.h>

#define IN_F   512
#define OUT_F  512
#define GRID_N 8
#define BATCH  4096
#define KDIM   (IN_F * 9)        // 4608
#define SPLITK 4
#define KCHUNK (KDIM / SPLITK)   // 1152
#define BM 128
#define BN 256
#define BK 64
#define NSTEPS (KCHUNK / BK)     // 18

typedef __fp16 half8 __attribute__((ext_vector_type(8)));
typedef float  f32x4 __attribute__((ext_vector_type(4)));

__device__ __forceinline__ void gload16(const void* gsrc, void* ldst) {
  __builtin_amdgcn_global_load_lds(
      (__attribute__((address_space(1))) void*)(void*)gsrc,
      (__attribute__((address_space(3))) void*)ldst, 16, 0, 0);
}

// ------- prep: feature expansion Phi[b][g*512+i] + weight pack -------------
__global__ void prep_kernel(const float* __restrict__ x, const float* __restrict__ grid,
                            const float* __restrict__ sw, const float* __restrict__ ba,
                            __fp16* __restrict__ A, __fp16* __restrict__ W) {
  const int bid = blockIdx.x;
  if (bid < (BATCH * IN_F) / 256) {            // ---- feat path ----
    const int idx = bid * 256 + threadIdx.x;   // b*512 + i
    const float xn = tanhf(x[idx]);
    const int b = idx >> 9;
    const int i = idx & (IN_F - 1);
    __fp16* arow = A + (size_t)b * KDIM + i;
#pragma unroll
    for (int g = 0; g < GRID_N; ++g) {
      const float d  = fabsf(xn - grid[g]);
      const float dd = d * d;
      const float inner = 1.0f - 6.0f * dd + 6.0f * dd * d;
      const float om = 1.0f - d;
      const float outer = 2.0f * om * om * om;
      const float bas = (d < 0.5f) ? inner : ((d < 1.0f) ? outer : 0.0f);
      arow[g * IN_F] = (__fp16)bas;
    }
    arow[8 * IN_F] = (__fp16)xn;
  } else {                                     // ---- weight path ----
    const int idx = (bid - (BATCH * IN_F) / 256) * 256 + threadIdx.x;  // o*512+i
    const float* swp = sw + (size_t)idx * GRID_N;
    __fp16* wrow = W + (size_t)(idx >> 9) * KDIM + (idx & (IN_F - 1));
#pragma unroll
    for (int g = 0; g < GRID_N; ++g) wrow[g * IN_F] = (__fp16)swp[g];
    wrow[8 * IN_F] = (__fp16)(0.1f * ba[idx]);
  }
}

// ------- split-K GEMM: P[z][m][n] = Phi_chunk . Wp_chunk^T -----------------
// 128x256 tile, 8 waves (2x4) of 64x64, BK=64, double-buffered LDS (96 KB),
// 2-phase pipeline: stage(k+1) issued after top barrier, compute(k) overlaps.
// XCD mapping: wgid&7 -> (n,z) pair so each XCD's 32 blocks share one 0.59MB
// B-chunk in its private L2. XOR-swizzled LDS (source-side + read-side).
__global__ __launch_bounds__(512, 2) void gemm_kernel(const __fp16* __restrict__ A,
                                                      const __fp16* __restrict__ W,
                                                      float* __restrict__ P) {
  __shared__ __align__(16) __fp16 As[2][BM * BK];   // 2 x 16 KB
  __shared__ __align__(16) __fp16 Bs[2][BN * BK];   // 2 x 32 KB
  const int tid  = threadIdx.x;
  const int lane = tid & 63;
  const int fr   = lane & 15;
  const int g4   = lane >> 4;
  const int wv   = tid >> 6;       // 0..7
  const int wm   = wv >> 2;        // 0..1
  const int wn   = wv & 3;         // 0..3
  const int wg   = blockIdx.x;
  const int nz   = wg & 7;         // HW round-robins wgid%8 across XCDs
  const int mb   = wg >> 3;        // 0..31
  const int m0   = mb * BM;
  const int n0   = (nz & 1) * BN;
  const int kbase = (nz >> 1) * KCHUNK;

  // staging: chunk c = j*512 + tid (16B units); row r = c>>3 (8 chunks/row);
  // global col-chunk pre-swizzled by ^(r&7); LDS dest linear (gload_lds rule).
  const __fp16* Ag[2];
  const __fp16* Bg[4];
  int lAoff[2], lBoff[4];
#pragma unroll
  for (int j = 0; j < 2; ++j) {
    const int c = j * 512 + tid;
    const int r = c >> 3;
    const int cc = (c & 7) ^ (r & 7);
    Ag[j] = A + (size_t)(m0 + r) * KDIM + kbase + cc * 8;
    lAoff[j] = c * 8;
  }
#pragma unroll
  for (int j = 0; j < 4; ++j) {
    const int c = j * 512 + tid;
    const int r = c >> 3;
    const int cc = (c & 7) ^ (r & 7);
    Bg[j] = W + (size_t)(n0 + r) * KDIM + kbase + cc * 8;
    lBoff[j] = c * 8;
  }

  f32x4 acc[4][4] = {};

  // prologue: stage k-step 0 into buf 0
#pragma unroll
  for (int j = 0; j < 2; ++j) gload16(Ag[j], &As[0][lAoff[j]]);
#pragma unroll
  for (int j = 0; j < 4; ++j) gload16(Bg[j], &Bs[0][lBoff[j]]);

  int cur = 0;
  for (int kt = 0; kt < NSTEPS; ++kt) {
    __syncthreads();   // drains vmcnt+lgkmcnt: buf[cur] resident, prev reads done
    if (kt + 1 < NSTEPS) {
      const int koff = (kt + 1) * BK;
#pragma unroll
      for (int j = 0; j < 2; ++j) gload16(Ag[j] + koff, &As[cur ^ 1][lAoff[j]]);
#pragma unroll
      for (int j = 0; j < 4; ++j) gload16(Bg[j] + koff, &Bs[cur ^ 1][lBoff[j]]);
    }
#pragma unroll
    for (int ks = 0; ks < 2; ++ks) {
      half8 a[4], b[4];
#pragma unroll
      for (int mi = 0; mi < 4; ++mi) {
        const int row = wm * 64 + mi * 16 + fr;
        const int ch = (ks * 4 + g4) ^ (fr & 7);
        a[mi] = *(const half8*)&As[cur][row * BK + ch * 8];
      }
#pragma unroll
      for (int ni = 0; ni < 4; ++ni) {
        const int row = wn * 64 + ni * 16 + fr;
        const int ch = (ks * 4 + g4) ^ (fr & 7);
        b[ni] = *(const half8*)&Bs[cur][row * BK + ch * 8];
      }
#pragma unroll
      for (int mi = 0; mi < 4; ++mi)
#pragma unroll
        for (int ni = 0; ni < 4; ++ni)
          acc[mi][ni] = __builtin_amdgcn_mfma_f32_16x16x32_f16(a[mi], b[ni], acc[mi][ni], 0, 0, 0);
    }
    cur ^= 1;
  }

  float* Pp = P + (size_t)(nz >> 1) * (BATCH * OUT_F);
#pragma unroll
  for (int mi = 0; mi < 4; ++mi) {
#pragma unroll
    for (int ni = 0; ni < 4; ++ni) {
      const int row = m0 + wm * 64 + mi * 16 + g4 * 4;   // C/D: row=(lane>>4)*4+reg
      const int col = n0 + wn * 64 + ni * 16 + fr;       //      col=lane&15
#pragma unroll
      for (int rg = 0; rg < 4; ++rg)
        Pp[(size_t)(row + rg) * OUT_F + col] = acc[mi][ni][rg];
    }
  }
}

// ------- reduce 4 split-K partials -----------------------------------------
__global__ void reduce_kernel(const float* __restrict__ P, float* __restrict__ out) {
  const int idx = blockIdx.x * 256 + threadIdx.x;
  const f32x4* P4 = (const f32x4*)P;
  const int stride = (BATCH * OUT_F) / 4;
  f32x4 s = P4[idx] + P4[idx + stride] + P4[idx + 2 * stride] + P4[idx + 3 * stride];
  ((f32x4*)out)[idx] = s;
}

extern "C" void kernel_launch(void* const* d_in, const int* in_sizes, int n_in,
                              void* d_out, int out_size, void* d_ws, size_t ws_size,
                              hipStream_t stream) {
  const float* x  = (const float*)d_in[0];
  const float* sw = (const float*)d_in[1];
  const float* ba = (const float*)d_in[2];
  const float* gp = (const float*)d_in[3];
  float* out = (float*)d_out;

  char* ws = (char*)d_ws;
  const size_t A_BYTES = (size_t)BATCH * KDIM * 2;   // 37,748,736
  const size_t W_BYTES = (size_t)OUT_F * KDIM * 2;   //  4,718,592
  __fp16* A = (__fp16*)ws;
  __fp16* W = (__fp16*)(ws + A_BYTES);
  float*  P = (float*)(ws + A_BYTES + W_BYTES);      // 32 MB f32 partials

  const int FEAT_BLKS = (BATCH * IN_F) / 256;        // 8192
  const int WT_BLKS   = (OUT_F * IN_F) / 256;        // 1024
  prep_kernel<<<FEAT_BLKS + WT_BLKS, 256, 0, stream>>>(x, gp, sw, ba, A, W);
  gemm_kernel<<<(BATCH / BM) * (OUT_F / BN) * SPLITK, 512, 0, stream>>>(A, W, P);
  reduce_kernel<<<(BATCH * OUT_F) / 4 / 256, 256, 0, stream>>>(P, out);
}

// Round 4
// 106.878 us; speedup vs baseline: 1.0770x; 1.0770x over previous
//
#include <hip/hip_runtime.h>

#define IN_F   512
#define OUT_F  512
#define GRID_N 8
#define BATCH  4096
#define KDIM   (IN_F * 9)        // 4608
#define SPLITK 8
#define KCHUNK (KDIM / SPLITK)   // 576
#define BK     64
#define NSTEPS (KCHUNK / BK)     // 9

typedef __fp16 half8 __attribute__((ext_vector_type(8)));
typedef float  f32x4 __attribute__((ext_vector_type(4)));

__device__ __forceinline__ void gload16(const void* gsrc, void* ldst) {
  __builtin_amdgcn_global_load_lds(
      (__attribute__((address_space(1))) void*)(void*)gsrc,
      (__attribute__((address_space(3))) void*)ldst, 16, 0, 0);
}

// ------- prep: feature expansion Phi[b][g*512+i] + weight pack -------------
__global__ void prep_kernel(const float* __restrict__ x, const float* __restrict__ grid,
                            const float* __restrict__ sw, const float* __restrict__ ba,
                            __fp16* __restrict__ A, __fp16* __restrict__ W) {
  const int bid = blockIdx.x;
  if (bid < (BATCH * IN_F) / 256) {            // ---- feat path ----
    const int idx = bid * 256 + threadIdx.x;   // b*512 + i
    const float xn = tanhf(x[idx]);
    const int b = idx >> 9;
    const int i = idx & (IN_F - 1);
    __fp16* arow = A + (size_t)b * KDIM + i;
#pragma unroll
    for (int g = 0; g < GRID_N; ++g) {
      const float d  = fabsf(xn - grid[g]);
      const float dd = d * d;
      const float inner = 1.0f - 6.0f * dd + 6.0f * dd * d;
      const float om = 1.0f - d;
      const float outer = 2.0f * om * om * om;
      const float bas = (d < 0.5f) ? inner : ((d < 1.0f) ? outer : 0.0f);
      arow[g * IN_F] = (__fp16)bas;
    }
    arow[8 * IN_F] = (__fp16)xn;
  } else {                                     // ---- weight path ----
    const int idx = (bid - (BATCH * IN_F) / 256) * 256 + threadIdx.x;  // o*512+i
    const float* swp = sw + (size_t)idx * GRID_N;
    __fp16* wrow = W + (size_t)(idx >> 9) * KDIM + (idx & (IN_F - 1));
#pragma unroll
    for (int g = 0; g < GRID_N; ++g) wrow[g * IN_F] = (__fp16)swp[g];
    wrow[8 * IN_F] = (__fp16)(0.1f * ba[idx]);
  }
}

// ------- split-K GEMM: P[z][m][n] = Phi_chunk . Wp_chunk^T (fp16 partials) -
// r2 skeleton: 128x128 tile, 4 waves of 64x64, BK=64, single LDS buffer,
// 2-barrier loop, XOR-swizzled (source-side + read-side, conflict-free).
// New: splitK=8 (grid 1024 -> 3+ blocks/CU), z = wgid&7 so each XCD's L2
// holds its own A/B K-chunk slice (A re-read served from L2, not L3).
__global__ __launch_bounds__(256, 3) void gemm_kernel(const __fp16* __restrict__ A,
                                                      const __fp16* __restrict__ W,
                                                      __fp16* __restrict__ P) {
  __shared__ __align__(16) __fp16 As[128 * BK];
  __shared__ __align__(16) __fp16 Bs[128 * BK];
  const int tid  = threadIdx.x;
  const int lane = tid & 63;
  const int wv   = tid >> 6;
  const int wm   = wv >> 1;
  const int wn   = wv & 1;
  const int wg   = blockIdx.x;
  const int z    = wg & 7;          // XCD id == K-chunk id (wgid%8 round-robin)
  const int t    = wg >> 3;         // 0..127
  const int m0   = (t >> 2) * 128;
  const int n0   = (t & 3) * 128;
  const int kbase = z * KCHUNK;

  // staging: issue tile t4 = wv*4+j covers halves [t4*512, +512):
  // rows r = t4*8 + lane/8, global col-chunk pre-swizzled by ^(r&7),
  // LDS dest linear (global_load_lds writes base + lane*16).
  const __fp16* Ag[4];
  const __fp16* Wg[4];
  __fp16* lA[4];
  __fp16* lB[4];
#pragma unroll
  for (int j = 0; j < 4; ++j) {
    const int t4 = wv * 4 + j;
    const int r = t4 * 8 + (lane >> 3);
    const int cs = ((lane & 7) ^ (r & 7)) * 8;
    Ag[j] = A + (size_t)(m0 + r) * KDIM + kbase + cs;
    Wg[j] = W + (size_t)(n0 + r) * KDIM + kbase + cs;
    lA[j] = &As[t4 * 512];
    lB[j] = &Bs[t4 * 512];
  }

  const int fr = lane & 15;
  const int g4 = lane >> 4;
  const int xr = fr & 7;               // read-side row-XOR (row&7 == fr&7)

  f32x4 acc[4][4] = {};

  for (int kt = 0; kt < NSTEPS; ++kt) {
#pragma unroll
    for (int j = 0; j < 4; ++j) {
      gload16(Ag[j], lA[j]);
      gload16(Wg[j], lB[j]);
      Ag[j] += BK; Wg[j] += BK;
    }
    __syncthreads();                   // drains vmcnt: tile resident

    half8 a[2][4], b[2][4];
#pragma unroll
    for (int ks = 0; ks < 2; ++ks) {
#pragma unroll
      for (int mi = 0; mi < 4; ++mi) {
        const int row = wm * 64 + mi * 16 + fr;
        const int ch = (ks * 4 + g4) ^ xr;
        a[ks][mi] = *(const half8*)&As[row * BK + ch * 8];
      }
#pragma unroll
      for (int ni = 0; ni < 4; ++ni) {
        const int row = wn * 64 + ni * 16 + fr;
        const int ch = (ks * 4 + g4) ^ xr;
        b[ks][ni] = *(const half8*)&Bs[row * BK + ch * 8];
      }
    }
#pragma unroll
    for (int ks = 0; ks < 2; ++ks)
#pragma unroll
      for (int mi = 0; mi < 4; ++mi)
#pragma unroll
        for (int ni = 0; ni < 4; ++ni)
          acc[ks ? 1 : 0][0] = acc[ks ? 1 : 0][0],  // no-op; keep structure simple
          acc[mi][ni] = __builtin_amdgcn_mfma_f32_16x16x32_f16(a[ks][mi], b[ks][ni], acc[mi][ni], 0, 0, 0);
    __syncthreads();
  }

  __fp16* Pp = P + (size_t)z * (BATCH * OUT_F);
#pragma unroll
  for (int mi = 0; mi < 4; ++mi) {
#pragma unroll
    for (int ni = 0; ni < 4; ++ni) {
      const int row = m0 + wm * 64 + mi * 16 + g4 * 4;   // C/D: row=(lane>>4)*4+reg
      const int col = n0 + wn * 64 + ni * 16 + fr;       //      col=lane&15
#pragma unroll
      for (int rg = 0; rg < 4; ++rg)
        Pp[(size_t)(row + rg) * OUT_F + col] = (__fp16)acc[mi][ni][rg];
    }
  }
}

// ------- reduce 8 fp16 split-K partials ------------------------------------
__global__ void reduce_kernel(const __fp16* __restrict__ P, float* __restrict__ out) {
  const int idx = blockIdx.x * 256 + threadIdx.x;   // half8 group, 0..262143
  float s[8] = {};
#pragma unroll
  for (int zz = 0; zz < SPLITK; ++zz) {
    const half8 v = *(const half8*)&P[(size_t)zz * (BATCH * OUT_F) + (size_t)idx * 8];
#pragma unroll
    for (int e = 0; e < 8; ++e) s[e] += (float)v[e];
  }
  f32x4 lo = {s[0], s[1], s[2], s[3]};
  f32x4 hi = {s[4], s[5], s[6], s[7]};
  ((f32x4*)out)[idx * 2]     = lo;
  ((f32x4*)out)[idx * 2 + 1] = hi;
}

extern "C" void kernel_launch(void* const* d_in, const int* in_sizes, int n_in,
                              void* d_out, int out_size, void* d_ws, size_t ws_size,
                              hipStream_t stream) {
  const float* x  = (const float*)d_in[0];
  const float* sw = (const float*)d_in[1];
  const float* ba = (const float*)d_in[2];
  const float* gp = (const float*)d_in[3];
  float* out = (float*)d_out;

  char* ws = (char*)d_ws;
  const size_t A_BYTES = (size_t)BATCH * KDIM * 2;   // 37,748,736
  const size_t W_BYTES = (size_t)OUT_F * KDIM * 2;   //  4,718,592
  __fp16* A = (__fp16*)ws;
  __fp16* W = (__fp16*)(ws + A_BYTES);
  __fp16* P = (__fp16*)(ws + A_BYTES + W_BYTES);     // 8 x 4 MB fp16 partials

  const int FEAT_BLKS = (BATCH * IN_F) / 256;        // 8192
  const int WT_BLKS   = (OUT_F * IN_F) / 256;        // 1024
  prep_kernel<<<FEAT_BLKS + WT_BLKS, 256, 0, stream>>>(x, gp, sw, ba, A, W);
  gemm_kernel<<<(BATCH / 128) * (OUT_F / 128) * SPLITK, 256, 0, stream>>>(A, W, P);
  reduce_kernel<<<(BATCH * OUT_F) / 8 / 256, 256, 0, stream>>>(P, out);
}